// Round 10
// baseline (185.716 us; speedup 1.0000x reference)
//
#include <hip/hip_runtime.h>
#include <hip/hip_fp16.h>

// AKConv fp32 in/out, fp16 MFMA everywhere (R10: bf16 -> fp16 dtype swap).
// WHY fp16: baseline absmax sat EXACTLY at the 0.0625 tolerance threshold;
// any codegen perturbation (fma regrouping is module-global in hipcc) flipped
// pass/fail by ulps (explains R1/R2/R3/R5/R9 failures vs R4/R6/R7/R8 passes).
// fp16 has 3 more mantissa bits than bf16 -> every rounding error (x corners,
// staged bilinear, weights) shrinks 8x -> absmax ~0.008, robust margin.
// Same MFMA shape/throughput (16x16x32_f16), same layouts, same instr count.
//  k_prep  : {BN fold + A-frag pre-swizzles} U {x -> xH/xHlo channel-last}
//  k_offset: 3x3 offset conv via double-fp16 MFMA + bilinear idx/wgt tables.
//  k_main  : R7 loop structure (loads issued AFTER the barrier - never cross
//            __syncthreads, avoiding hipcc's vmcnt(0)-before-s_barrier drain
//            that cost R8 +21us) + XOR bank-swizzle on Bs (conflicts 3.58M->0).

typedef __attribute__((ext_vector_type(8))) _Float16 half8;
typedef __attribute__((ext_vector_type(4))) float f32x4;

#define Bsz 8
#define C1 128
#define C2 256
#define HW 6400
#define NP 5

// ---- workspace layout (bytes) ---- identical region map to R0.
#define NPOS (Bsz*NP*HW)                    // 256000 samples
#define WS_IDX4 0                           // int4[NPOS]: corner BYTE offsets into xH image
#define WS_WGT4 (WS_IDX4 + NPOS*16)         // float4[NPOS]
#define WS_XT   (WS_WGT4 + NPOS*16)         // ushort xH[8][6400][128]   13.1 MB (fp16 hi)
#define WS_XTLO (WS_XT + Bsz*HW*C1*2)       // ushort xHlo[...]          13.1 MB (fp16 residual)
#define WS_ACW  (WS_XTLO + Bsz*HW*C1*2)     // ushort acw[163840] (fp16)
#define WS_APWH (WS_ACW + C2*C1*NP*2)       // ushort apw_hi[18432] (fp16)
#define WS_APWL (WS_APWH + 18432*2)         // ushort apw_lo[18432] (fp16)
#define WS_BNS  (WS_APWL + 18432*2)
#define WS_BNT  (WS_BNS + 1024)

__device__ __forceinline__ unsigned short f2h(float f) {
  __half h = __float2half(f);
  return reinterpret_cast<unsigned short&>(h);
}
__device__ __forceinline__ float h2f(unsigned short u) {
  __half h = reinterpret_cast<__half&>(u);
  return __half2float(h);
}

// ---- K0: fused pre-swizzle (blocks 0..711) + transpose (blocks 712..2311) ---
__global__ __launch_bounds__(256) void k_prep(
    const float* __restrict__ x, const float* __restrict__ cw,
    const float* __restrict__ pw,
    const float* __restrict__ gam, const float* __restrict__ bet,
    const float* __restrict__ mu, const float* __restrict__ var,
    unsigned short* __restrict__ xH, unsigned short* __restrict__ xHlo,
    unsigned short* __restrict__ acw, unsigned short* __restrict__ apwh,
    unsigned short* __restrict__ apwl,
    float* __restrict__ bns, float* __restrict__ bnt) {
  __shared__ float lds[128][33];
  int t = threadIdx.x;
  if (blockIdx.x < 712) {
    int i = blockIdx.x * 256 + t;
    if (i < 163840) {
      int j = i & 7, lane = (i >> 3) & 63, mtile = (i >> 9) & 15;
      int cc = (i >> 13) & 3, k = i >> 15;
      int m = mtile * 16 + (lane & 15);
      int c = cc * 32 + (lane >> 4) * 8 + j;
      acw[i] = f2h(cw[(m * C1 + c) * NP + k]);
    } else {
      int i2 = i - 163840;
      int j = i2 & 7, lane = (i2 >> 3) & 63, chunk = i2 >> 9;
      int m = lane & 15, tap = chunk >> 2;
      int c = (chunk & 3) * 32 + (lane >> 4) * 8 + j;
      float wv = (m < 10) ? pw[(m * C1 + c) * 9 + tap] : 0.f;
      unsigned short hi = f2h(wv);
      apwh[i2] = hi;
      apwl[i2] = f2h(wv - h2f(hi));
    }
    if (blockIdx.x == 0) {
      float s = gam[t] * rsqrtf(var[t] + 1e-5f);
      bns[t] = s;
      bnt[t] = bet[t] - mu[t] * s;
    }
    return;
  }
  int gp0 = (blockIdx.x - 712) * 32;
  int b = gp0 / HW, p0 = gp0 - b * HW;
  const float* xb = x + (size_t)b * C1 * HW;
  int q = t & 7, r = t >> 3;
#pragma unroll
  for (int pass = 0; pass < 4; ++pass) {
    int c = pass * 32 + r;
    float4 v = *(const float4*)(xb + (size_t)c * HW + p0 + q * 4);
    lds[c][q * 4 + 0] = v.x;
    lds[c][q * 4 + 1] = v.y;
    lds[c][q * 4 + 2] = v.z;
    lds[c][q * 4 + 3] = v.w;
  }
  __syncthreads();
  int px = t >> 3, u = t & 7;
#pragma unroll
  for (int it = 0; it < 2; ++it) {
    int unit = it * 8 + u;
    int c0 = unit * 8;
    unsigned short vh[8], vl[8];
#pragma unroll
    for (int e = 0; e < 8; ++e) {
      float f = lds[c0 + e][px];
      unsigned short h = f2h(f);
      vh[e] = h;
      vl[e] = f2h(f - h2f(h));
    }
    size_t base = (size_t)(gp0 + px) * C1 + unit * 8;
    *(uint4*)(xH + base) = *(uint4*)vh;
    *(uint4*)(xHlo + base) = *(uint4*)vl;
  }
}

// ---- K1: offset conv via double-fp16 MFMA + LDS pixel patch ---------------
__global__ __launch_bounds__(256) void k_offset(
    const unsigned short* __restrict__ xH, const unsigned short* __restrict__ xHlo,
    const unsigned short* __restrict__ apwh, const unsigned short* __restrict__ apwl,
    const float* __restrict__ pb,
    int4* __restrict__ idx4, float4* __restrict__ wgt4) {
  __shared__ __align__(16) char patch[2 * 6 * 18 * 80];   // 17,280 B
  __shared__ float sOff[4][10][16];

  int t = threadIdx.x, wave = t >> 6, lane = t & 63;
  int n16 = lane & 15, koct = lane >> 4;
  int blk = blockIdx.x;                            // 800 = 8b x 20tr x 5tc
  int b = blk / 100;
  int rem = blk - b * 100;
  int h0 = (rem / 5) * 4, w0 = (rem % 5) * 16;
  const char* xTb  = (const char*)xH  + (size_t)b * HW * 256;
  const char* xTlb = (const char*)xHlo + (size_t)b * HW * 256;

  f32x4 acc = (f32x4)(0.f);
#pragma unroll
  for (int cc = 0; cc < 4; ++cc) {
    __syncthreads();                               // patch free to overwrite
    // ---- stage patch: 864 16B-units (432 hi + 432 lo)
    for (int u = t; u < 864; u += 256) {
      int half = (u >= 432) ? 1 : 0;
      int r2 = u - half * 432;
      int unit = r2 & 3, slot = r2 >> 2;
      int pr = slot / 18, pc = slot - pr * 18;
      int r = h0 - 1 + pr, c = w0 - 1 + pc;
      uint4 v = make_uint4(0u, 0u, 0u, 0u);
      if (((unsigned)r < 80u) && ((unsigned)c < 80u)) {
        const char* src = (half ? xTlb : xTb) + (((r * 80 + c) << 8) + cc * 64 + unit * 16);
        v = *(const uint4*)src;
      }
      *(uint4*)(patch + half * 8640 + slot * 80 + unit * 16) = v;
    }
    __syncthreads();                               // patch ready
#pragma unroll
    for (int tap = 0; tap < 9; ++tap) {
      int dh = tap / 3, dw = tap - dh * 3;         // 0..2
      int lo = (((wave + dh) * 18) + (n16 + dw)) * 80 + koct * 16;
      half8 bh = *(const half8*)(patch + lo);
      half8 bl = *(const half8*)(patch + 8640 + lo);
      half8 ah = *(const half8*)(apwh + ((tap * 4 + cc) * 64 + lane) * 8);
      half8 al = *(const half8*)(apwl + ((tap * 4 + cc) * 64 + lane) * 8);
      acc = __builtin_amdgcn_mfma_f32_16x16x32_f16(ah, bh, acc, 0, 0, 0);
      acc = __builtin_amdgcn_mfma_f32_16x16x32_f16(ah, bl, acc, 0, 0, 0);
      acc = __builtin_amdgcn_mfma_f32_16x16x32_f16(al, bh, acc, 0, 0, 0);
    }
  }

  int quad = lane >> 4;
#pragma unroll
  for (int r = 0; r < 4; ++r) {
    int row = quad * 4 + r;
    if (row < 10) sOff[wave][row][n16] = acc[r];
  }
  __syncthreads();

  for (int task = t; task < 320; task += 256) {
    int wv = task / 80, rem2 = task - wv * 80, k = rem2 >> 4, n = rem2 & 15;
    int h2 = h0 + wv, w2 = w0 + n;
    int p2 = h2 * 80 + w2;
    float px = sOff[wv][k][n] + pb[k] + (float)(h2 + (k >> 1));
    float py = sOff[wv][5 + k][n] + pb[5 + k] + (float)(w2 + (k & 1));
    float pf = floorf(px), qf = floorf(py);
    float x0 = fminf(fmaxf(pf, 0.f), 79.f);
    float x1 = fminf(fmaxf(pf + 1.f, 0.f), 79.f);
    float y0 = fminf(fmaxf(qf, 0.f), 79.f);
    float y1 = fminf(fmaxf(qf + 1.f, 0.f), 79.f);
    float pxc = fminf(fmaxf(px, 0.f), 79.f);
    float pyc = fminf(fmaxf(py, 0.f), 79.f);
    float wx0 = 1.f + (x0 - pxc), wx1 = 1.f - (x1 - pxc);
    float wy0 = 1.f + (y0 - pyc), wy1 = 1.f - (y1 - pyc);
    int ix0 = (int)x0, ix1 = (int)x1, iy0 = (int)y0, iy1 = (int)y1;
    int g = (b * NP + k) * HW + p2;
    idx4[g] = make_int4((ix0 * 80 + iy0) << 8, (ix1 * 80 + iy1) << 8,
                        (ix0 * 80 + iy1) << 8, (ix1 * 80 + iy0) << 8);
    wgt4[g] = make_float4(wx0 * wy0, wx1 * wy1, wx0 * wy1, wx1 * wy0);
  }
}

// ---- K3 staging: R7 lane-remap + XOR bank-swizzle --------------------------
// Bs slot s = (cc*2+grp)*64 + j*16 + p4 stored at s ^ (u&7); read side applies
// the same involution (((lane>>4)&3) ^ ((cc&1)<<2)). Bijective; each 16-lane
// phase permutes within its own 16-slot set -> reads conflict-free, writes
// spread over 8 bank groups (2-way = free).
__device__ __forceinline__ void stage_load(
    const char* xTb, const int4* __restrict__ idx4, const float4* __restrict__ wgt4,
    size_t sampBase, int k, int wave, int lane,
    uint4 q[2][4], float4 wg[2]) {
  int u = lane & 15, sq = lane >> 4;
  int choff = u * 16;
#pragma unroll
  for (int set = 0; set < 2; ++set) {
    int sb = wave * 8 + set * 4 + sq;
    size_t g = sampBase + (size_t)k * HW + sb;
    int4 id = idx4[g];
    wg[set] = wgt4[g];
    q[set][0] = *(const uint4*)(xTb + id.x + choff);   // lt
    q[set][1] = *(const uint4*)(xTb + id.y + choff);   // rb
    q[set][2] = *(const uint4*)(xTb + id.z + choff);   // lb
    q[set][3] = *(const uint4*)(xTb + id.w + choff);   // rt
  }
}

__device__ __forceinline__ void stage_store(
    unsigned short* BsBuf, int wave, int lane,
    uint4 q[2][4], float4 wg[2]) {
  int u = lane & 15, sq = lane >> 4;
  int cc = u >> 2, j = u & 3;                 // channel octet = cc*4 + j
#pragma unroll
  for (int set = 0; set < 2; ++set) {
    int sb = wave * 8 + set * 4 + sq;
    int grp = sb >> 4, p4 = sb & 15;
    const unsigned short* a0 = (const unsigned short*)&q[set][0];
    const unsigned short* a1 = (const unsigned short*)&q[set][1];
    const unsigned short* a2 = (const unsigned short*)&q[set][2];
    const unsigned short* a3 = (const unsigned short*)&q[set][3];
    union { uint4 v; unsigned short us[8]; } rr;
#pragma unroll
    for (int e = 0; e < 8; ++e) {
      float f = wg[set].x * h2f(a0[e]) + wg[set].y * h2f(a1[e])
              + wg[set].z * h2f(a2[e]) + wg[set].w * h2f(a3[e]);
      rr.us[e] = f2h(f);
    }
    int slot = ((cc * 2 + grp) * 64 + j * 16 + p4) ^ (u & 7);   // XOR swizzle
    *(uint4*)&BsBuf[slot * 8] = rr.v;
  }
}

__global__ __launch_bounds__(512) void k_main(
    const unsigned short* __restrict__ xH,
    const unsigned short* __restrict__ acw,
    const int4* __restrict__ idx4, const float4* __restrict__ wgt4,
    const float* __restrict__ bns, const float* __restrict__ bnt,
    float* __restrict__ out) {
  __shared__ unsigned short Bs[2][2][8 * 64 * 8];  // [half][dbuf] 2 x 2 x 8 KB

  int half = threadIdx.x >> 8;
  int t = threadIdx.x & 255;
  int gp0 = blockIdx.x * 64 + half * 32;
  int b = gp0 / HW, pbase = gp0 - b * HW;
  int wave = t >> 6, lane = t & 63;
  const char* xTb = (const char*)xH + (size_t)b * HW * 256;
  size_t sampBase = (size_t)b * NP * HW + pbase;

  f32x4 acc[4][2];
#pragma unroll
  for (int mt = 0; mt < 4; ++mt)
#pragma unroll
    for (int nt = 0; nt < 2; ++nt) acc[mt][nt] = (f32x4)(0.f);

  uint4 pf[2][4];
  float4 pwg[2];
  stage_load(xTb, idx4, wgt4, sampBase, 0, wave, lane, pf, pwg);
  stage_store(Bs[half][0], wave, lane, pf, pwg);

#pragma unroll
  for (int k = 0; k < NP; ++k) {
    __syncthreads();                    // Bs[half][k&1] staged for all waves
    // R7 placement: issue next-k gathers AFTER the barrier so they never
    // cross a __syncthreads (hipcc drains vmcnt(0) before s_barrier).
    if (k + 1 < NP)
      stage_load(xTb, idx4, wgt4, sampBase, k + 1, wave, lane, pf, pwg);
    const unsigned short* Bk = Bs[half][k & 1];
#pragma unroll
    for (int cc = 0; cc < 4; ++cc) {
      half8 bfr[2];
#pragma unroll
      for (int nt = 0; nt < 2; ++nt) {
        int rs = ((cc * 2 + nt) * 64 + lane)
                 ^ ((lane >> 4) & 3) ^ ((cc & 1) << 2);         // XOR swizzle
        bfr[nt] = *(const half8*)&Bk[rs * 8];
      }
      const unsigned short* ab =
          acw + (size_t)((((k * 4 + cc) * 16) + wave * 4) * 64 + lane) * 8;
#pragma unroll
      for (int mt = 0; mt < 4; ++mt) {
        half8 a = *(const half8*)(ab + mt * 64 * 8);
#pragma unroll
        for (int nt = 0; nt < 2; ++nt)
          acc[mt][nt] = __builtin_amdgcn_mfma_f32_16x16x32_f16(
              a, bfr[nt], acc[mt][nt], 0, 0, 0);
      }
    }
    if (k + 1 < NP)
      stage_store(Bs[half][(k + 1) & 1], wave, lane, pf, pwg);
  }

  // ---- epilogue: BN + SiLU
  int quad = lane >> 4, col = lane & 15;
#pragma unroll
  for (int mt = 0; mt < 4; ++mt) {
    int m0 = wave * 64 + mt * 16 + quad * 4;
#pragma unroll
    for (int r = 0; r < 4; ++r) {
      int m = m0 + r;
      float s = bns[m], sh = bnt[m];
      float* op = out + ((size_t)(b * C2 + m)) * HW + pbase;
#pragma unroll
      for (int nt = 0; nt < 2; ++nt) {
        float y = fmaf(acc[mt][nt][r], s, sh);
        op[nt * 16 + col] = y * (1.f / (1.f + __expf(-y)));
      }
    }
  }
}

extern "C" void kernel_launch(void* const* d_in, const int* in_sizes, int n_in,
                              void* d_out, int out_size, void* d_ws, size_t ws_size,
                              hipStream_t stream) {
  const float* x  = (const float*)d_in[0];
  const float* pw = (const float*)d_in[1];
  const float* pb = (const float*)d_in[2];
  const float* cw = (const float*)d_in[3];
  const float* bg = (const float*)d_in[4];
  const float* bb = (const float*)d_in[5];
  const float* bm = (const float*)d_in[6];
  const float* bv = (const float*)d_in[7];
  float* out = (float*)d_out;

  char* ws = (char*)d_ws;
  int4*           idx4 = (int4*)(ws + WS_IDX4);
  float4*         wgt4 = (float4*)(ws + WS_WGT4);
  unsigned short* xH   = (unsigned short*)(ws + WS_XT);
  unsigned short* xHlo = (unsigned short*)(ws + WS_XTLO);
  unsigned short* acw  = (unsigned short*)(ws + WS_ACW);
  unsigned short* apwh = (unsigned short*)(ws + WS_APWH);
  unsigned short* apwl = (unsigned short*)(ws + WS_APWL);
  float*          bns  = (float*)(ws + WS_BNS);
  float*          bnt  = (float*)(ws + WS_BNT);

  k_prep<<<2312, 256, 0, stream>>>(x, cw, pw, bg, bb, bm, bv,
                                   xH, xHlo, acw, apwh, apwl, bns, bnt);
  k_offset<<<800, 256, 0, stream>>>(xH, xHlo, apwh, apwl, pb, idx4, wgt4);
  k_main<<<800, 512, 0, stream>>>(xH, acw, idx4, wgt4, bns, bnt, out);
}

// Round 12
// 163.664 us; speedup vs baseline: 1.1347x; 1.1347x over previous
//
#include <hip/hip_runtime.h>
#include <hip/hip_bf16.h>

// AKConv fp32 in/out, bf16 MFMA everywhere.
//  k_prep  : fused {BN fold + A-frag pre-swizzles} U {x -> xT/xTlo channel-last}
//  k_offset: 3x3 offset conv via double-bf16 MFMA with LDS-tiled pixel patch
//            + bilinear idx/wgt tables to global. (byte-identical to R0)
//  k_main  : R6 512-thread shell (two independent 256-thread halves). R7:
//            gather lane-remap - each load instr covers one corner of 4
//            samples x 256B contiguous (4 address clusters vs 16 x 64B),
//            attacking the TA transaction bound (MfmaUtil 9%, HBM 16%, all
//            pipes idle). Per-element combine expression, idx4/wgt4 values,
//            Bs image, GEMM and epilogue are bitwise identical to R0/R6.

typedef __attribute__((ext_vector_type(8))) short short8;
typedef __attribute__((ext_vector_type(4))) float f32x4;

#define Bsz 8
#define C1 128
#define C2 256
#define HW 6400
#define NP 5

// ---- workspace layout (bytes) ---- identical to R0.
#define NPOS (Bsz*NP*HW)                    // 256000 samples
#define WS_IDX4 0                           // int4[NPOS]: corner BYTE offsets into xT image
#define WS_WGT4 (WS_IDX4 + NPOS*16)         // float4[NPOS]
#define WS_XT   (WS_WGT4 + NPOS*16)         // ushort xT[8][6400][128]   13.1 MB (hi)
#define WS_XTLO (WS_XT + Bsz*HW*C1*2)       // ushort xTlo[...]          13.1 MB (residual)
#define WS_ACW  (WS_XTLO + Bsz*HW*C1*2)     // ushort acw[163840]
#define WS_APWH (WS_ACW + C2*C1*NP*2)       // ushort apw_hi[18432]
#define WS_APWL (WS_APWH + 18432*2)         // ushort apw_lo[18432]
#define WS_BNS  (WS_APWL + 18432*2)
#define WS_BNT  (WS_BNS + 1024)

__device__ __forceinline__ unsigned short f2bf(float f) {
  __hip_bfloat16 h = __float2bfloat16(f);
  return reinterpret_cast<unsigned short&>(h);
}
__device__ __forceinline__ float bfu2f(unsigned short u) {
  unsigned int v = ((unsigned int)u) << 16;
  return reinterpret_cast<float&>(v);
}

// ---- K0: fused pre-swizzle (blocks 0..711) + transpose (blocks 712..2311) ---
__global__ __launch_bounds__(256) void k_prep(
    const float* __restrict__ x, const float* __restrict__ cw,
    const float* __restrict__ pw,
    const float* __restrict__ gam, const float* __restrict__ bet,
    const float* __restrict__ mu, const float* __restrict__ var,
    unsigned short* __restrict__ xT, unsigned short* __restrict__ xTlo,
    unsigned short* __restrict__ acw, unsigned short* __restrict__ apwh,
    unsigned short* __restrict__ apwl,
    float* __restrict__ bns, float* __restrict__ bnt) {
  __shared__ float lds[128][33];
  int t = threadIdx.x;
  if (blockIdx.x < 712) {
    int i = blockIdx.x * 256 + t;
    if (i < 163840) {
      int j = i & 7, lane = (i >> 3) & 63, mtile = (i >> 9) & 15;
      int cc = (i >> 13) & 3, k = i >> 15;
      int m = mtile * 16 + (lane & 15);
      int c = cc * 32 + (lane >> 4) * 8 + j;
      acw[i] = f2bf(cw[(m * C1 + c) * NP + k]);
    } else {
      int i2 = i - 163840;
      int j = i2 & 7, lane = (i2 >> 3) & 63, chunk = i2 >> 9;
      int m = lane & 15, tap = chunk >> 2;
      int c = (chunk & 3) * 32 + (lane >> 4) * 8 + j;
      float wv = (m < 10) ? pw[(m * C1 + c) * 9 + tap] : 0.f;
      unsigned short hi = f2bf(wv);
      apwh[i2] = hi;
      apwl[i2] = f2bf(wv - bfu2f(hi));
    }
    if (blockIdx.x == 0) {
      float s = gam[t] * rsqrtf(var[t] + 1e-5f);
      bns[t] = s;
      bnt[t] = bet[t] - mu[t] * s;
    }
    return;
  }
  int gp0 = (blockIdx.x - 712) * 32;
  int b = gp0 / HW, p0 = gp0 - b * HW;
  const float* xb = x + (size_t)b * C1 * HW;
  int q = t & 7, r = t >> 3;
#pragma unroll
  for (int pass = 0; pass < 4; ++pass) {
    int c = pass * 32 + r;
    float4 v = *(const float4*)(xb + (size_t)c * HW + p0 + q * 4);
    lds[c][q * 4 + 0] = v.x;
    lds[c][q * 4 + 1] = v.y;
    lds[c][q * 4 + 2] = v.z;
    lds[c][q * 4 + 3] = v.w;
  }
  __syncthreads();
  int px = t >> 3, u = t & 7;
#pragma unroll
  for (int it = 0; it < 2; ++it) {
    int unit = it * 8 + u;
    int c0 = unit * 8;
    unsigned short vh[8], vl[8];
#pragma unroll
    for (int e = 0; e < 8; ++e) {
      float f = lds[c0 + e][px];
      unsigned short h = f2bf(f);
      vh[e] = h;
      vl[e] = f2bf(f - bfu2f(h));
    }
    size_t base = (size_t)(gp0 + px) * C1 + unit * 8;
    *(uint4*)(xT + base) = *(uint4*)vh;
    *(uint4*)(xTlo + base) = *(uint4*)vl;
  }
}

// ---- K1: offset conv via double-bf16 MFMA + LDS pixel patch ---------------
__global__ __launch_bounds__(256) void k_offset(
    const unsigned short* __restrict__ xT, const unsigned short* __restrict__ xTlo,
    const unsigned short* __restrict__ apwh, const unsigned short* __restrict__ apwl,
    const float* __restrict__ pb,
    int4* __restrict__ idx4, float4* __restrict__ wgt4) {
  __shared__ __align__(16) char patch[2 * 6 * 18 * 80];   // 17,280 B
  __shared__ float sOff[4][10][16];

  int t = threadIdx.x, wave = t >> 6, lane = t & 63;
  int n16 = lane & 15, koct = lane >> 4;
  int blk = blockIdx.x;                            // 800 = 8b x 20tr x 5tc
  int b = blk / 100;
  int rem = blk - b * 100;
  int h0 = (rem / 5) * 4, w0 = (rem % 5) * 16;
  const char* xTb  = (const char*)xT  + (size_t)b * HW * 256;
  const char* xTlb = (const char*)xTlo + (size_t)b * HW * 256;

  f32x4 acc = (f32x4)(0.f);
#pragma unroll
  for (int cc = 0; cc < 4; ++cc) {
    __syncthreads();                               // patch free to overwrite
    // ---- stage patch: 864 16B-units (432 hi + 432 lo)
    for (int u = t; u < 864; u += 256) {
      int half = (u >= 432) ? 1 : 0;
      int r2 = u - half * 432;
      int unit = r2 & 3, slot = r2 >> 2;
      int pr = slot / 18, pc = slot - pr * 18;
      int r = h0 - 1 + pr, c = w0 - 1 + pc;
      uint4 v = make_uint4(0u, 0u, 0u, 0u);
      if (((unsigned)r < 80u) && ((unsigned)c < 80u)) {
        const char* src = (half ? xTlb : xTb) + (((r * 80 + c) << 8) + cc * 64 + unit * 16);
        v = *(const uint4*)src;
      }
      *(uint4*)(patch + half * 8640 + slot * 80 + unit * 16) = v;
    }
    __syncthreads();                               // patch ready
#pragma unroll
    for (int tap = 0; tap < 9; ++tap) {
      int dh = tap / 3, dw = tap - dh * 3;         // 0..2
      int lo = (((wave + dh) * 18) + (n16 + dw)) * 80 + koct * 16;
      short8 bh = *(const short8*)(patch + lo);
      short8 bl = *(const short8*)(patch + 8640 + lo);
      short8 ah = *(const short8*)(apwh + ((tap * 4 + cc) * 64 + lane) * 8);
      short8 al = *(const short8*)(apwl + ((tap * 4 + cc) * 64 + lane) * 8);
      acc = __builtin_amdgcn_mfma_f32_16x16x32_bf16(ah, bh, acc, 0, 0, 0);
      acc = __builtin_amdgcn_mfma_f32_16x16x32_bf16(ah, bl, acc, 0, 0, 0);
      acc = __builtin_amdgcn_mfma_f32_16x16x32_bf16(al, bh, acc, 0, 0, 0);
    }
  }

  int quad = lane >> 4;
#pragma unroll
  for (int r = 0; r < 4; ++r) {
    int row = quad * 4 + r;
    if (row < 10) sOff[wave][row][n16] = acc[r];
  }
  __syncthreads();

  for (int task = t; task < 320; task += 256) {
    int wv = task / 80, rem2 = task - wv * 80, k = rem2 >> 4, n = rem2 & 15;
    int h2 = h0 + wv, w2 = w0 + n;
    int p2 = h2 * 80 + w2;
    float px = sOff[wv][k][n] + pb[k] + (float)(h2 + (k >> 1));
    float py = sOff[wv][5 + k][n] + pb[5 + k] + (float)(w2 + (k & 1));
    float pf = floorf(px), qf = floorf(py);
    float x0 = fminf(fmaxf(pf, 0.f), 79.f);
    float x1 = fminf(fmaxf(pf + 1.f, 0.f), 79.f);
    float y0 = fminf(fmaxf(qf, 0.f), 79.f);
    float y1 = fminf(fmaxf(qf + 1.f, 0.f), 79.f);
    float pxc = fminf(fmaxf(px, 0.f), 79.f);
    float pyc = fminf(fmaxf(py, 0.f), 79.f);
    float wx0 = 1.f + (x0 - pxc), wx1 = 1.f - (x1 - pxc);
    float wy0 = 1.f + (y0 - pyc), wy1 = 1.f - (y1 - pyc);
    int ix0 = (int)x0, ix1 = (int)x1, iy0 = (int)y0, iy1 = (int)y1;
    int g = (b * NP + k) * HW + p2;
    idx4[g] = make_int4((ix0 * 80 + iy0) << 8, (ix1 * 80 + iy1) << 8,
                        (ix0 * 80 + iy1) << 8, (ix1 * 80 + iy0) << 8);
    wgt4[g] = make_float4(wx0 * wy0, wx1 * wy1, wx0 * wy1, wx1 * wy0);
  }
}

// ---- K3 staging: R7 lane-remap, per-element math bitwise == R0 -------------
// Lane l: u = l&15 (channel unit, bytes u*16..u*16+15 of the 256B pixel
// record), sq = l>>4 (sample). Per set (2 sets): sample sb = wave*8+set*4+sq.
// Each load instruction = one corner of 4 samples x 256B contiguous
// (4 address clusters). Thread holds all 4 corners of its sample at its
// channel octet -> combine is the verbatim R0 expression with R0 weights.
__device__ __forceinline__ void stage_load(
    const char* xTb, const int4* __restrict__ idx4, const float4* __restrict__ wgt4,
    size_t sampBase, int k, int wave, int lane,
    uint4 q[2][4], float4 wg[2]) {
  int u = lane & 15, sq = lane >> 4;
  int choff = u * 16;
#pragma unroll
  for (int set = 0; set < 2; ++set) {
    int sb = wave * 8 + set * 4 + sq;
    size_t g = sampBase + (size_t)k * HW + sb;
    int4 id = idx4[g];
    wg[set] = wgt4[g];
    q[set][0] = *(const uint4*)(xTb + id.x + choff);   // lt
    q[set][1] = *(const uint4*)(xTb + id.y + choff);   // rb
    q[set][2] = *(const uint4*)(xTb + id.z + choff);   // lb
    q[set][3] = *(const uint4*)(xTb + id.w + choff);   // rt
  }
}

__device__ __forceinline__ void stage_store(
    unsigned short* BsBuf, int wave, int lane,
    uint4 q[2][4], float4 wg[2]) {
  int u = lane & 15, sq = lane >> 4;
  int cc = u >> 2, j = u & 3;                 // channel octet = cc*4 + j
#pragma unroll
  for (int set = 0; set < 2; ++set) {
    int sb = wave * 8 + set * 4 + sq;
    int grp = sb >> 4, p4 = sb & 15;
    const unsigned short* a0 = (const unsigned short*)&q[set][0];
    const unsigned short* a1 = (const unsigned short*)&q[set][1];
    const unsigned short* a2 = (const unsigned short*)&q[set][2];
    const unsigned short* a3 = (const unsigned short*)&q[set][3];
    union { uint4 v; unsigned short us[8]; } rr;
#pragma unroll
    for (int e = 0; e < 8; ++e) {
      float f = wg[set].x * bfu2f(a0[e]) + wg[set].y * bfu2f(a1[e])
              + wg[set].z * bfu2f(a2[e]) + wg[set].w * bfu2f(a3[e]);
      rr.us[e] = f2bf(f);
    }
    *(uint4*)&BsBuf[((cc * 2 + grp) * 64 + j * 16 + p4) * 8] = rr.v;
  }
}

__global__ __launch_bounds__(512) void k_main(
    const unsigned short* __restrict__ xT,
    const unsigned short* __restrict__ acw,
    const int4* __restrict__ idx4, const float4* __restrict__ wgt4,
    const float* __restrict__ bns, const float* __restrict__ bnt,
    float* __restrict__ out) {
  __shared__ unsigned short Bs[2][2][8 * 64 * 8];  // [half][dbuf] 2 x 2 x 8 KB

  int half = threadIdx.x >> 8;
  int t = threadIdx.x & 255;
  int gp0 = blockIdx.x * 64 + half * 32;
  int b = gp0 / HW, pbase = gp0 - b * HW;
  int wave = t >> 6, lane = t & 63;
  const char* xTb = (const char*)xT + (size_t)b * HW * 256;
  size_t sampBase = (size_t)b * NP * HW + pbase;

  f32x4 acc[4][2];
#pragma unroll
  for (int mt = 0; mt < 4; ++mt)
#pragma unroll
    for (int nt = 0; nt < 2; ++nt) acc[mt][nt] = (f32x4)(0.f);

  uint4 pf[2][4];
  float4 pwg[2];
  stage_load(xTb, idx4, wgt4, sampBase, 0, wave, lane, pf, pwg);
  stage_store(Bs[half][0], wave, lane, pf, pwg);

#pragma unroll
  for (int k = 0; k < NP; ++k) {
    __syncthreads();                    // Bs[half][k&1] staged for all waves
    if (k + 1 < NP)
      stage_load(xTb, idx4, wgt4, sampBase, k + 1, wave, lane, pf, pwg);
    const unsigned short* Bk = Bs[half][k & 1];
#pragma unroll
    for (int cc = 0; cc < 4; ++cc) {
      short8 bfr[2];
#pragma unroll
      for (int nt = 0; nt < 2; ++nt)
        bfr[nt] = *(const short8*)&Bk[((cc * 2 + nt) * 64 + lane) * 8];
      const unsigned short* ab =
          acw + (size_t)((((k * 4 + cc) * 16) + wave * 4) * 64 + lane) * 8;
#pragma unroll
      for (int mt = 0; mt < 4; ++mt) {
        short8 a = *(const short8*)(ab + mt * 64 * 8);
#pragma unroll
        for (int nt = 0; nt < 2; ++nt)
          acc[mt][nt] = __builtin_amdgcn_mfma_f32_16x16x32_bf16(
              a, bfr[nt], acc[mt][nt], 0, 0, 0);
      }
    }
    if (k + 1 < NP)
      stage_store(Bs[half][(k + 1) & 1], wave, lane, pf, pwg);
  }

  // ---- epilogue: BN + SiLU
  int quad = lane >> 4, col = lane & 15;
#pragma unroll
  for (int mt = 0; mt < 4; ++mt) {
    int m0 = wave * 64 + mt * 16 + quad * 4;
#pragma unroll
    for (int r = 0; r < 4; ++r) {
      int m = m0 + r;
      float s = bns[m], sh = bnt[m];
      float* op = out + ((size_t)(b * C2 + m)) * HW + pbase;
#pragma unroll
      for (int nt = 0; nt < 2; ++nt) {
        float y = fmaf(acc[mt][nt][r], s, sh);
        op[nt * 16 + col] = y * (1.f / (1.f + __expf(-y)));
      }
    }
  }
}

extern "C" void kernel_launch(void* const* d_in, const int* in_sizes, int n_in,
                              void* d_out, int out_size, void* d_ws, size_t ws_size,
                              hipStream_t stream) {
  const float* x  = (const float*)d_in[0];
  const float* pw = (const float*)d_in[1];
  const float* pb = (const float*)d_in[2];
  const float* cw = (const float*)d_in[3];
  const float* bg = (const float*)d_in[4];
  const float* bb = (const float*)d_in[5];
  const float* bm = (const float*)d_in[6];
  const float* bv = (const float*)d_in[7];
  float* out = (float*)d_out;

  char* ws = (char*)d_ws;
  int4*           idx4 = (int4*)(ws + WS_IDX4);
  float4*         wgt4 = (float4*)(ws + WS_WGT4);
  unsigned short* xT   = (unsigned short*)(ws + WS_XT);
  unsigned short* xTlo = (unsigned short*)(ws + WS_XTLO);
  unsigned short* acw  = (unsigned short*)(ws + WS_ACW);
  unsigned short* apwh = (unsigned short*)(ws + WS_APWH);
  unsigned short* apwl = (unsigned short*)(ws + WS_APWL);
  float*          bns  = (float*)(ws + WS_BNS);
  float*          bnt  = (float*)(ws + WS_BNT);

  k_prep<<<2312, 256, 0, stream>>>(x, cw, pw, bg, bb, bm, bv,
                                   xT, xTlo, acw, apwh, apwl, bns, bnt);
  k_offset<<<800, 256, 0, stream>>>(xT, xTlo, apwh, apwl, pb, idx4, wgt4);
  k_main<<<800, 512, 0, stream>>>(xT, acw, idx4, wgt4, bns, bnt, out);
}